// Round 7
// baseline (148.302 us; speedup 1.0000x reference)
//
#include <hip/hip_runtime.h>
#include <hip/hip_bf16.h>

#define HW 16384   // 128*128
#define CC 64
#define BB 4

typedef __attribute__((ext_vector_type(8))) short bf8;   // 8 bf16 (4 VGPRs)
typedef __attribute__((ext_vector_type(4))) float f4;    // MFMA C/D frag

static __device__ __forceinline__ float bf2f(unsigned short u) {
    return __uint_as_float(((unsigned)u) << 16);
}
static __device__ __forceinline__ unsigned short f2bf(float f) {
    __hip_bfloat16 h = __float2bfloat16(f);   // RNE
    return *reinterpret_cast<unsigned short*>(&h);
}

// ---------------------------------------------------------------------------
// K0: weight repack (blocks 0..215) + x transpose via LDS (blocks 216..1239).
//  wA  [32][576] bf16 : wA[m][t*64+c] = w_off[m][c][t]   (rows 27..31 zero)
//  Wal [64][576] bf16 : Wal[o][t*64+c] = w_align[o][c][t]
//  xT  [b*HW+hw][c]   : channels contiguous (128B rows)
// ---------------------------------------------------------------------------
__global__ __launch_bounds__(256) void k_prep_tx(const float* __restrict__ x,
                                                 const float* __restrict__ w_off,
                                                 const float* __restrict__ w_align,
                                                 unsigned short* __restrict__ xT,
                                                 unsigned short* __restrict__ wA,
                                                 unsigned short* __restrict__ Wal) {
    __shared__ unsigned T32[64 * 33];   // 8448 B
    int bx = blockIdx.x, t = threadIdx.x;
    if (bx < 216) {
        int i = bx * 256 + t;
        if (i < 32 * 576) {
            int m = i / 576, r = i - m * 576, tt = r >> 6, c = r & 63;
            float v = (m < 27) ? w_off[m * 576 + c * 9 + tt] : 0.f;
            wA[i] = f2bf(v);
        } else {
            int j = i - 32 * 576;   // j < 64*576 by grid construction
            int o = j / 576, r = j - o * 576, tt = r >> 6, c = r & 63;
            Wal[j] = f2bf(w_align[o * 576 + c * 9 + tt]);
        }
        return;
    }
    int pix0 = (bx - 216) * 64;
    int b = pix0 >> 14, hw0 = pix0 & (HW - 1);
    const float* xb = x + (size_t)b * CC * HW + hw0;
#pragma unroll
    for (int u = 0; u < 8; u++) {
        int i = t + 256 * u;                 // 2048 = 32 cp x 64 p
        int cp = i >> 6, p = i & 63;
        float v0 = xb[(size_t)(2 * cp) * HW + p];
        float v1 = xb[(size_t)(2 * cp + 1) * HW + p];
        T32[p * 33 + cp] = (unsigned)f2bf(v0) | ((unsigned)f2bf(v1) << 16);
    }
    __syncthreads();
#pragma unroll
    for (int u = 0; u < 2; u++) {
        int i = t + 256 * u;                 // 512 = 64 p x 8 q
        int p = i >> 3, q = i & 7;
        uint4 qq;
        qq.x = T32[p * 33 + q * 4 + 0];
        qq.y = T32[p * 33 + q * 4 + 1];
        qq.z = T32[p * 33 + q * 4 + 2];
        qq.w = T32[p * 33 + q * 4 + 3];
        *(uint4*)(xT + ((size_t)b * HW + hw0 + p) * CC + q * 8) = qq;
    }
}

// ---------------------------------------------------------------------------
// K1: offset conv, 9-tap shifted MFMA GEMM, weights in LDS (pad 576->584).
// ---------------------------------------------------------------------------
__global__ __launch_bounds__(256, 4) void k_conv(const unsigned short* __restrict__ xT,
                                                 const unsigned short* __restrict__ wA,
                                                 const float* __restrict__ b_off,
                                                 float* __restrict__ off) {
    __shared__ __align__(16) unsigned short WL[32 * 584];   // 37376 B
    int t = threadIdx.x, lane = t & 63, wv = t >> 6;
    int quad = lane >> 4, col = lane & 15;
#pragma unroll
    for (int u = 0; u < 9; u++) {
        int idx = t + 256 * u;               // 2304 = 32 rows x 72 uint4
        int row = idx / 72, jb = idx - row * 72;
        *(uint4*)(WL + row * 584 + jb * 8) = ((const uint4*)wA)[idx];
    }
    __syncthreads();

    int n = blockIdx.x * 64 + wv * 16 + col;           // global pixel
    int b = n >> 14, hw = n & (HW - 1), h = hw >> 7, w = hw & 127;
    const unsigned short* xTb = xT + (size_t)b * HW * CC;
    const bf8 zero = {0, 0, 0, 0, 0, 0, 0, 0};

    f4 acc0 = {0.f, 0.f, 0.f, 0.f};
    f4 acc1 = {0.f, 0.f, 0.f, 0.f};
#pragma unroll
    for (int tap = 0; tap < 9; tap++) {
        int dyt = tap / 3 - 1, dxt = tap - (tap / 3) * 3 - 1;
        int hs = h + dyt, ws = w + dxt;
        bool valid = ((unsigned)hs < 128u) && ((unsigned)ws < 128u);
        int hc = min(max(hs, 0), 127), wc = min(max(ws, 0), 127);
        const unsigned short* src = xTb + ((size_t)(hc * 128 + wc)) * CC + quad * 8;
        bf8 b0 = *(const bf8*)(src);
        bf8 b1 = *(const bf8*)(src + 32);
        b0 = valid ? b0 : zero;
        b1 = valid ? b1 : zero;
        const unsigned short* l0 = WL + col * 584 + tap * 64 + quad * 8;
        const unsigned short* l1 = WL + (col + 16) * 584 + tap * 64 + quad * 8;
        acc0 = __builtin_amdgcn_mfma_f32_16x16x32_bf16(*(const bf8*)l0, b0, acc0, 0, 0, 0);
        acc1 = __builtin_amdgcn_mfma_f32_16x16x32_bf16(*(const bf8*)l1, b0, acc1, 0, 0, 0);
        acc0 = __builtin_amdgcn_mfma_f32_16x16x32_bf16(*(const bf8*)(l0 + 32), b1, acc0, 0, 0, 0);
        acc1 = __builtin_amdgcn_mfma_f32_16x16x32_bf16(*(const bf8*)(l1 + 32), b1, acc1, 0, 0, 0);
    }
#pragma unroll
    for (int i = 0; i < 4; i++) {
        int o0 = quad * 4 + i;                          // 0..15, always < 27
        {
            float v = acc0[i] + b_off[o0];
            if (o0 >= 18) v = 2.f / (1.f + __expf(-v));
            off[((size_t)b * 27 + o0) * HW + hw] = v;
        }
        int o1 = 16 + o0;
        if (o1 < 27) {
            float v = acc1[i] + b_off[o1];
            if (o1 >= 18) v = 2.f / (1.f + __expf(-v));
            off[((size_t)b * 27 + o1) * HW + hw] = v;
        }
    }
}

// ---------------------------------------------------------------------------
// K2: tap-parallel sampler. grid = (1024 px-chunks, 9 taps).
// Thread = (pixel, 16-ch quarter). Chain depth 1: off-load -> 8 independent
// 16B gathers -> lerp -> one 32B store to S[pg][k*64+c] (B-frag layout).
// Massive TLP (36.9k waves) hides all gather latency.
// ---------------------------------------------------------------------------
__global__ __launch_bounds__(256, 8) void k_sample(const unsigned short* __restrict__ xT,
                                                   const float* __restrict__ off,
                                                   unsigned short* __restrict__ S) {
    int t = threadIdx.x;
    int k = blockIdx.y;
    int pxl = t >> 2, cq = t & 3;                      // 64 px x 4 ch-quarters
    int pg = blockIdx.x * 64 + pxl;                    // global pixel
    int b = pg >> 14, hw = pg & (HW - 1), h = hw >> 7, w = hw & 127;
    const unsigned short* xTb = xT + (size_t)b * HW * CC;
    const float* offb = off + (size_t)b * 27 * HW + hw;

    float dy = offb[(size_t)(2 * k) * HW];
    float dx = offb[(size_t)(2 * k + 1) * HW];
    float m  = offb[(size_t)(18 + k) * HW];
    int k3 = k / 3;
    float ys = (float)(h + k3 - 1) + dy;
    float xs = (float)(w + (k - 3 * k3) - 1) + dx;
    float y0f = floorf(ys), x0f = floorf(xs);
    float fy = ys - y0f, fx = xs - x0f;
    int y0 = (int)y0f, x0 = (int)x0f;
    int y1 = y0 + 1, x1 = x0 + 1;
    bool vy0 = (unsigned)y0 < 128u, vy1 = (unsigned)y1 < 128u;
    bool vx0 = (unsigned)x0 < 128u, vx1 = (unsigned)x1 < 128u;
    int cy0 = min(max(y0, 0), 127), cy1 = min(max(y1, 0), 127);
    int cx0 = min(max(x0, 0), 127), cx1 = min(max(x1, 0), 127);
    float w00 = (1.f - fy) * (1.f - fx) * ((vy0 && vx0) ? m : 0.f);
    float w01 = (1.f - fy) * fx         * ((vy0 && vx1) ? m : 0.f);
    float w10 = fy * (1.f - fx)         * ((vy1 && vx0) ? m : 0.f);
    float w11 = fy * fx                 * ((vy1 && vx1) ? m : 0.f);

    const unsigned short* c00 = xTb + ((size_t)(cy0 * 128 + cx0)) * CC + cq * 16;
    const unsigned short* c01 = xTb + ((size_t)(cy0 * 128 + cx1)) * CC + cq * 16;
    const unsigned short* c10 = xTb + ((size_t)(cy1 * 128 + cx0)) * CC + cq * 16;
    const unsigned short* c11 = xTb + ((size_t)(cy1 * 128 + cx1)) * CC + cq * 16;
    uint4 qa0 = *(const uint4*)(c00),     qa1 = *(const uint4*)(c01);
    uint4 qa2 = *(const uint4*)(c10),     qa3 = *(const uint4*)(c11);
    uint4 qb0 = *(const uint4*)(c00 + 8), qb1 = *(const uint4*)(c01 + 8);
    uint4 qb2 = *(const uint4*)(c10 + 8), qb3 = *(const uint4*)(c11 + 8);

    unsigned short* dst = S + (size_t)pg * 576 + k * 64 + cq * 16;
#pragma unroll
    for (int h2 = 0; h2 < 2; h2++) {
        const unsigned short* u00 = (const unsigned short*)(h2 ? &qb0 : &qa0);
        const unsigned short* u01 = (const unsigned short*)(h2 ? &qb1 : &qa1);
        const unsigned short* u10 = (const unsigned short*)(h2 ? &qb2 : &qa2);
        const unsigned short* u11 = (const unsigned short*)(h2 ? &qb3 : &qa3);
        unsigned short ov[8];
#pragma unroll
        for (int j = 0; j < 8; j++) {
            float v = w00 * bf2f(u00[j]) + w01 * bf2f(u01[j])
                    + w10 * bf2f(u10[j]) + w11 * bf2f(u11[j]);
            ov[j] = f2bf(v);
        }
        uint4 qq;
        qq.x = ov[0] | ((unsigned)ov[1] << 16);
        qq.y = ov[2] | ((unsigned)ov[3] << 16);
        qq.z = ov[4] | ((unsigned)ov[5] << 16);
        qq.w = ov[6] | ((unsigned)ov[7] << 16);
        *(uint4*)(dst + h2 * 8) = qq;
    }
}

// ---------------------------------------------------------------------------
// K3: einsum GEMM. grid = (1024 px-chunks, 2 out-halves). Weights (32 rows)
// staged in LDS fragment-major: WL4[f], f = row + 32*(s*4+quad) -> both the
// staging writes (bank 4t%32) and A-frag reads (bank 4col%32) are <=2-way.
// Per wave: 16 px x 32 outs; 18 sequential S-loads (prefetchable) + 36 MFMA.
// ---------------------------------------------------------------------------
__global__ __launch_bounds__(256, 4) void k_gemm(const unsigned short* __restrict__ S,
                                                 const unsigned short* __restrict__ Wal,
                                                 const float* __restrict__ b_align,
                                                 float* __restrict__ wten) {
    __shared__ __align__(16) uint4 WL4[32 * 72];   // 36864 B
    int t = threadIdx.x, lane = t & 63, wv = t >> 6;
    int quad = lane >> 4, col = lane & 15;
    int half = blockIdx.y;
    const uint4* Wal4 = (const uint4*)Wal;
#pragma unroll
    for (int u = 0; u < 9; u++) {
        int f = t + 256 * u;                  // 2304 = 32 rows x 72 frags
        WL4[f] = Wal4[(half * 32 + (f & 31)) * 72 + (f >> 5)];
    }
    __syncthreads();

    int pg = blockIdx.x * 64 + wv * 16 + col;
    int b = pg >> 14, hw = pg & (HW - 1);
    const unsigned short* srow = S + (size_t)pg * 576 + quad * 8;

    f4 acc0 = {0.f, 0.f, 0.f, 0.f};
    f4 acc1 = {0.f, 0.f, 0.f, 0.f};
#pragma unroll
    for (int s = 0; s < 18; s++) {
        bf8 bfrag = *(const bf8*)(srow + s * 32);
        bf8 a0 = *(const bf8*)&WL4[col + 32 * (s * 4 + quad)];
        bf8 a1 = *(const bf8*)&WL4[16 + col + 32 * (s * 4 + quad)];
        acc0 = __builtin_amdgcn_mfma_f32_16x16x32_bf16(a0, bfrag, acc0, 0, 0, 0);
        acc1 = __builtin_amdgcn_mfma_f32_16x16x32_bf16(a1, bfrag, acc1, 0, 0, 0);
    }
    int ob = half * 32;
    float* wb = wten + (size_t)b * CC * HW + hw;
#pragma unroll
    for (int i = 0; i < 4; i++) {
        {
            int o = ob + quad * 4 + i;
            float u = acc0[i] + b_align[o];
            float sg = 1.f / (1.f + __expf(-u));
            wb[(size_t)o * HW] = __expf(sg);
        }
        {
            int o = ob + 16 + quad * 4 + i;
            float u = acc1[i] + b_align[o];
            float sg = 1.f / (1.f + __expf(-u));
            wb[(size_t)o * HW] = __expf(sg);
        }
    }
}

// ---------------------------------------------------------------------------
// K4: out = pool3s2(w*x)/pool3s2(w) (the /9 cancels; zero-pad taps drop out).
// ---------------------------------------------------------------------------
__global__ __launch_bounds__(256) void k_pool(const float* __restrict__ x,
                                              const float* __restrict__ wten,
                                              float* __restrict__ out) {
    int idx = blockIdx.x * 256 + threadIdx.x;
    int ow = idx & 63;
    int oh = (idx >> 6) & 63;
    int bc = idx >> 12;
    const float* wp = wten + (size_t)bc * HW;
    const float* xp = x + (size_t)bc * HW;
    float num = 0.f, den = 0.f;
#pragma unroll
    for (int iy = 0; iy < 3; iy++) {
        int y = 2 * oh + iy - 1;
        if ((unsigned)y >= 128u) continue;
#pragma unroll
        for (int ix = 0; ix < 3; ix++) {
            int xc = 2 * ow + ix - 1;
            if ((unsigned)xc >= 128u) continue;
            float wv = wp[y * 128 + xc];
            float xv = xp[y * 128 + xc];
            num = fmaf(wv, xv, num);
            den += wv;
        }
    }
    out[idx] = num / den;
}

// ---------------------------------------------------------------------------
extern "C" void kernel_launch(void* const* d_in, const int* in_sizes, int n_in,
                              void* d_out, int out_size, void* d_ws, size_t ws_size,
                              hipStream_t stream) {
    const float* x       = (const float*)d_in[0];
    const float* w_off   = (const float*)d_in[1];
    const float* b_off   = (const float*)d_in[2];
    const float* w_align = (const float*)d_in[3];
    const float* b_align = (const float*)d_in[4];
    float* out = (float*)d_out;

    // workspace layout (~108 MB of the 256 MiB ws):
    char* p = (char*)d_ws;
    float* off  = (float*)p;                  p += (size_t)BB * 27 * HW * 4;  // 7.08 MB
    float* wten = (float*)p;                  p += (size_t)BB * CC * HW * 4;  // 16.78 MB
    unsigned short* xT  = (unsigned short*)p; p += (size_t)BB * HW * CC * 2;  // 8.39 MB
    unsigned short* wA  = (unsigned short*)p; p += 32 * 576 * 2;              // 36.9 KB
    unsigned short* Wal = (unsigned short*)p; p += 64 * 576 * 2;              // 73.7 KB
    unsigned short* S   = (unsigned short*)p;                                 // 75.5 MB

    k_prep_tx<<<dim3(1240), dim3(256), 0, stream>>>(x, w_off, w_align, xT, wA, Wal);
    k_conv<<<dim3(1024), dim3(256), 0, stream>>>(xT, wA, b_off, off);
    k_sample<<<dim3(1024, 9), dim3(256), 0, stream>>>(xT, off, S);
    k_gemm<<<dim3(1024, 2), dim3(256), 0, stream>>>(S, Wal, b_align, wten);
    k_pool<<<dim3(4096), dim3(256), 0, stream>>>(x, wten, out);
}

// Round 8
// 143.061 us; speedup vs baseline: 1.0366x; 1.0366x over previous
//
#include <hip/hip_runtime.h>
#include <hip/hip_bf16.h>

#define HW 16384   // 128*128
#define CC 64
#define BB 4

typedef __attribute__((ext_vector_type(8))) short bf8;   // 8 bf16 (4 VGPRs)
typedef __attribute__((ext_vector_type(4))) float f4;    // MFMA C/D frag

static __device__ __forceinline__ float bf2f(unsigned short u) {
    return __uint_as_float(((unsigned)u) << 16);
}
static __device__ __forceinline__ unsigned short f2bf(float f) {
    __hip_bfloat16 h = __float2bfloat16(f);   // RNE
    return *reinterpret_cast<unsigned short*>(&h);
}

// ---------------------------------------------------------------------------
// K0: weight repack (blocks 0..215) + x transpose via LDS (blocks 216..1239).
//  wA [32][576] bf16 : wA[m][t*64+c] = w_off[m][c][t]   (rows 27..31 zero)
//  W2 fragment-major : W2[(s*256 + row*4 + quad)*8 + j] = w_align[row][c][t]
//      with t = s>>1, c = (s&1)*32 + quad*8 + j
//      -> one A-frag load instruction (fixed s, mt) covers 64 lanes x 16B
//         CONTIGUOUS (1KB, 8 lines) -- L1-friendly, prefetchable.
//  xT [b*HW+hw][c]   : channels contiguous (128B rows)
// ---------------------------------------------------------------------------
__global__ __launch_bounds__(256) void k_prep_tx(const float* __restrict__ x,
                                                 const float* __restrict__ w_off,
                                                 const float* __restrict__ w_align,
                                                 unsigned short* __restrict__ xT,
                                                 unsigned short* __restrict__ wA,
                                                 unsigned short* __restrict__ W2) {
    __shared__ unsigned T32[64 * 33];   // 8448 B
    int bx = blockIdx.x, t = threadIdx.x;
    if (bx < 216) {
        int i = bx * 256 + t;
        if (i < 32 * 576) {
            int m = i / 576, r = i - m * 576, tt = r >> 6, c = r & 63;
            float v = (m < 27) ? w_off[m * 576 + c * 9 + tt] : 0.f;
            wA[i] = f2bf(v);
        } else {
            int j = i - 32 * 576;                 // 0..36863
            int f = j >> 3, jj = j & 7;
            int s = f >> 8, rem = f & 255;
            int row = rem >> 2, quad = rem & 3;
            int c = ((s & 1) << 5) + quad * 8 + jj;
            int tt = s >> 1;
            W2[j] = f2bf(w_align[row * 576 + c * 9 + tt]);
        }
        return;
    }
    int pix0 = (bx - 216) * 64;
    int b = pix0 >> 14, hw0 = pix0 & (HW - 1);
    const float* xb = x + (size_t)b * CC * HW + hw0;
#pragma unroll
    for (int u = 0; u < 8; u++) {
        int i = t + 256 * u;                 // 2048 = 32 cp x 64 p
        int cp = i >> 6, p = i & 63;
        float v0 = xb[(size_t)(2 * cp) * HW + p];
        float v1 = xb[(size_t)(2 * cp + 1) * HW + p];
        T32[p * 33 + cp] = (unsigned)f2bf(v0) | ((unsigned)f2bf(v1) << 16);
    }
    __syncthreads();
#pragma unroll
    for (int u = 0; u < 2; u++) {
        int i = t + 256 * u;                 // 512 = 64 p x 8 q
        int p = i >> 3, q = i & 7;
        uint4 qq;
        qq.x = T32[p * 33 + q * 4 + 0];
        qq.y = T32[p * 33 + q * 4 + 1];
        qq.z = T32[p * 33 + q * 4 + 2];
        qq.w = T32[p * 33 + q * 4 + 3];
        *(uint4*)(xT + ((size_t)b * HW + hw0 + p) * CC + q * 8) = qq;
    }
}

// ---------------------------------------------------------------------------
// K1: offset conv, 9-tap shifted MFMA GEMM, weights in LDS (pad 576->584).
// ---------------------------------------------------------------------------
__global__ __launch_bounds__(256, 4) void k_conv(const unsigned short* __restrict__ xT,
                                                 const unsigned short* __restrict__ wA,
                                                 const float* __restrict__ b_off,
                                                 float* __restrict__ off) {
    __shared__ __align__(16) unsigned short WL[32 * 584];   // 37376 B
    int t = threadIdx.x, lane = t & 63, wv = t >> 6;
    int quad = lane >> 4, col = lane & 15;
#pragma unroll
    for (int u = 0; u < 9; u++) {
        int idx = t + 256 * u;               // 2304 = 32 rows x 72 uint4
        int row = idx / 72, jb = idx - row * 72;
        *(uint4*)(WL + row * 584 + jb * 8) = ((const uint4*)wA)[idx];
    }
    __syncthreads();

    int n = blockIdx.x * 64 + wv * 16 + col;           // global pixel
    int b = n >> 14, hw = n & (HW - 1), h = hw >> 7, w = hw & 127;
    const unsigned short* xTb = xT + (size_t)b * HW * CC;
    const bf8 zero = {0, 0, 0, 0, 0, 0, 0, 0};

    f4 acc0 = {0.f, 0.f, 0.f, 0.f};
    f4 acc1 = {0.f, 0.f, 0.f, 0.f};
#pragma unroll
    for (int tap = 0; tap < 9; tap++) {
        int dyt = tap / 3 - 1, dxt = tap - (tap / 3) * 3 - 1;
        int hs = h + dyt, ws = w + dxt;
        bool valid = ((unsigned)hs < 128u) && ((unsigned)ws < 128u);
        int hc = min(max(hs, 0), 127), wc = min(max(ws, 0), 127);
        const unsigned short* src = xTb + ((size_t)(hc * 128 + wc)) * CC + quad * 8;
        bf8 b0 = *(const bf8*)(src);
        bf8 b1 = *(const bf8*)(src + 32);
        b0 = valid ? b0 : zero;
        b1 = valid ? b1 : zero;
        const unsigned short* l0 = WL + col * 584 + tap * 64 + quad * 8;
        const unsigned short* l1 = WL + (col + 16) * 584 + tap * 64 + quad * 8;
        acc0 = __builtin_amdgcn_mfma_f32_16x16x32_bf16(*(const bf8*)l0, b0, acc0, 0, 0, 0);
        acc1 = __builtin_amdgcn_mfma_f32_16x16x32_bf16(*(const bf8*)l1, b0, acc1, 0, 0, 0);
        acc0 = __builtin_amdgcn_mfma_f32_16x16x32_bf16(*(const bf8*)(l0 + 32), b1, acc0, 0, 0, 0);
        acc1 = __builtin_amdgcn_mfma_f32_16x16x32_bf16(*(const bf8*)(l1 + 32), b1, acc1, 0, 0, 0);
    }
#pragma unroll
    for (int i = 0; i < 4; i++) {
        int o0 = quad * 4 + i;                          // 0..15, always < 27
        {
            float v = acc0[i] + b_off[o0];
            if (o0 >= 18) v = 2.f / (1.f + __expf(-v));
            off[((size_t)b * 27 + o0) * HW + hw] = v;
        }
        int o1 = 16 + o0;
        if (o1 < 27) {
            float v = acc1[i] + b_off[o1];
            if (o1 >= 18) v = 2.f / (1.f + __expf(-v));
            off[((size_t)b * 27 + o1) * HW + hw] = v;
        }
    }
}

// ---------------------------------------------------------------------------
// K2 (fused, single-wave blocks): wave = 16 pixels x all 64 outputs.
// Lane (quad,col) samples channels quad*8(+32) of pixel col -> B-frags land
// directly in registers. A-frags loaded from fragment-major W2: each load
// instruction is 64 lanes x 16B CONTIGUOUS (8 lines), L1-cached.
// No LDS, no barriers, no sampling duplication. Grid = 4096 waves.
// ---------------------------------------------------------------------------
__global__ __launch_bounds__(64, 4) void k_fused(const unsigned short* __restrict__ xT,
                                                 const float* __restrict__ off,
                                                 const unsigned short* __restrict__ W2,
                                                 const float* __restrict__ b_align,
                                                 float* __restrict__ wten) {
    int lane = threadIdx.x;
    int quad = lane >> 4, col = lane & 15;
    int pix0 = blockIdx.x * 16;
    int b = pix0 >> 14;
    int px = (pix0 & (HW - 1)) + col;
    int h = px >> 7, w = px & 127;
    const unsigned short* xTb = xT + (size_t)b * HW * CC;
    const float* offp = off + (size_t)b * 27 * HW + px;

    f4 acc[4];
#pragma unroll
    for (int mt = 0; mt < 4; mt++) acc[mt] = (f4){0.f, 0.f, 0.f, 0.f};

#pragma unroll
    for (int k = 0; k < 9; k++) {
        float dy = offp[(size_t)(2 * k) * HW];
        float dx = offp[(size_t)(2 * k + 1) * HW];
        float m  = offp[(size_t)(18 + k) * HW];
        int k3 = k / 3;
        float ys = (float)(h + k3 - 1) + dy;
        float xs = (float)(w + (k - 3 * k3) - 1) + dx;
        float y0f = floorf(ys), x0f = floorf(xs);
        float fy = ys - y0f, fx = xs - x0f;
        int y0 = (int)y0f, x0 = (int)x0f;
        int y1 = y0 + 1, x1 = x0 + 1;
        bool vy0 = (unsigned)y0 < 128u, vy1 = (unsigned)y1 < 128u;
        bool vx0 = (unsigned)x0 < 128u, vx1 = (unsigned)x1 < 128u;
        int cy0 = min(max(y0, 0), 127), cy1 = min(max(y1, 0), 127);
        int cx0 = min(max(x0, 0), 127), cx1 = min(max(x1, 0), 127);
        float w00 = (1.f - fy) * (1.f - fx) * ((vy0 && vx0) ? m : 0.f);
        float w01 = (1.f - fy) * fx         * ((vy0 && vx1) ? m : 0.f);
        float w10 = fy * (1.f - fx)         * ((vy1 && vx0) ? m : 0.f);
        float w11 = fy * fx                 * ((vy1 && vx1) ? m : 0.f);

        const unsigned short* c00 = xTb + ((size_t)(cy0 * 128 + cx0)) * CC + quad * 8;
        const unsigned short* c01 = xTb + ((size_t)(cy0 * 128 + cx1)) * CC + quad * 8;
        const unsigned short* c10 = xTb + ((size_t)(cy1 * 128 + cx0)) * CC + quad * 8;
        const unsigned short* c11 = xTb + ((size_t)(cy1 * 128 + cx1)) * CC + quad * 8;
        uint4 qa0 = *(const uint4*)(c00),      qa1 = *(const uint4*)(c01);
        uint4 qa2 = *(const uint4*)(c10),      qa3 = *(const uint4*)(c11);
        uint4 qb0 = *(const uint4*)(c00 + 32), qb1 = *(const uint4*)(c01 + 32);
        uint4 qb2 = *(const uint4*)(c10 + 32), qb3 = *(const uint4*)(c11 + 32);

        bf8 bfrag[2];
#pragma unroll
        for (int h2 = 0; h2 < 2; h2++) {
            const unsigned short* u00 = (const unsigned short*)(h2 ? &qb0 : &qa0);
            const unsigned short* u01 = (const unsigned short*)(h2 ? &qb1 : &qa1);
            const unsigned short* u10 = (const unsigned short*)(h2 ? &qb2 : &qa2);
            const unsigned short* u11 = (const unsigned short*)(h2 ? &qb3 : &qa3);
            unsigned short ov[8];
#pragma unroll
            for (int j = 0; j < 8; j++) {
                float v = w00 * bf2f(u00[j]) + w01 * bf2f(u01[j])
                        + w10 * bf2f(u10[j]) + w11 * bf2f(u11[j]);
                ov[j] = f2bf(v);
            }
            bfrag[h2] = *(const bf8*)ov;
        }
#pragma unroll
        for (int h2 = 0; h2 < 2; h2++) {
            int s = 2 * k + h2;
#pragma unroll
            for (int mt = 0; mt < 4; mt++) {
                bf8 a = *(const bf8*)(W2 + ((size_t)(s * 256 + (mt * 16 + col) * 4 + quad)) * 8);
                acc[mt] = __builtin_amdgcn_mfma_f32_16x16x32_bf16(a, bfrag[h2], acc[mt], 0, 0, 0);
            }
        }
    }

    // ---- epilogue: bias + exp(sigmoid) ----
    float* wb = wten + (size_t)b * CC * HW + px;
#pragma unroll
    for (int mt = 0; mt < 4; mt++)
#pragma unroll
        for (int i = 0; i < 4; i++) {
            int o = mt * 16 + quad * 4 + i;
            float u = acc[mt][i] + b_align[o];
            float sg = 1.f / (1.f + __expf(-u));
            wb[(size_t)o * HW] = __expf(sg);
        }
}

// ---------------------------------------------------------------------------
// K3: out = pool3s2(w*x)/pool3s2(w) (the /9 cancels; zero-pad taps drop out).
// ---------------------------------------------------------------------------
__global__ __launch_bounds__(256) void k_pool(const float* __restrict__ x,
                                              const float* __restrict__ wten,
                                              float* __restrict__ out) {
    int idx = blockIdx.x * 256 + threadIdx.x;
    int ow = idx & 63;
    int oh = (idx >> 6) & 63;
    int bc = idx >> 12;
    const float* wp = wten + (size_t)bc * HW;
    const float* xp = x + (size_t)bc * HW;
    float num = 0.f, den = 0.f;
#pragma unroll
    for (int iy = 0; iy < 3; iy++) {
        int y = 2 * oh + iy - 1;
        if ((unsigned)y >= 128u) continue;
#pragma unroll
        for (int ix = 0; ix < 3; ix++) {
            int xc = 2 * ow + ix - 1;
            if ((unsigned)xc >= 128u) continue;
            float wv = wp[y * 128 + xc];
            float xv = xp[y * 128 + xc];
            num = fmaf(wv, xv, num);
            den += wv;
        }
    }
    out[idx] = num / den;
}

// ---------------------------------------------------------------------------
extern "C" void kernel_launch(void* const* d_in, const int* in_sizes, int n_in,
                              void* d_out, int out_size, void* d_ws, size_t ws_size,
                              hipStream_t stream) {
    const float* x       = (const float*)d_in[0];
    const float* w_off   = (const float*)d_in[1];
    const float* b_off   = (const float*)d_in[2];
    const float* w_align = (const float*)d_in[3];
    const float* b_align = (const float*)d_in[4];
    float* out = (float*)d_out;

    // workspace layout (~32.4 MB):
    char* p = (char*)d_ws;
    float* off  = (float*)p;                  p += (size_t)BB * 27 * HW * 4;  // 7.08 MB
    float* wten = (float*)p;                  p += (size_t)BB * CC * HW * 4;  // 16.78 MB
    unsigned short* xT  = (unsigned short*)p; p += (size_t)BB * HW * CC * 2;  // 8.39 MB
    unsigned short* wA  = (unsigned short*)p; p += 32 * 576 * 2;              // 36.9 KB
    unsigned short* W2  = (unsigned short*)p;                                 // 73.7 KB

    k_prep_tx<<<dim3(1240), dim3(256), 0, stream>>>(x, w_off, w_align, xT, wA, W2);
    k_conv<<<dim3(1024), dim3(256), 0, stream>>>(xT, wA, b_off, off);
    k_fused<<<dim3(4096), dim3(64), 0, stream>>>(xT, off, W2, b_align, wten);
    k_pool<<<dim3(4096), dim3(256), 0, stream>>>(x, wten, out);
}